// Round 14
// baseline (2356.397 us; speedup 1.0000x reference)
//
#include <hip/hip_runtime.h>

typedef unsigned short u16;
typedef unsigned int   u32;
typedef __attribute__((ext_vector_type(8))) short s8v;   // 8 x bf16 bits (4 VGPRs)
typedef __attribute__((ext_vector_type(4))) float f4v;   // MFMA accumulator
typedef __attribute__((ext_vector_type(4))) int   i4v;   // 4 VGPRs (generic 16B)

#define B_SZ  64
#define T_LEN 512
#define U_DIM 256
#define E_DIM 300
#define EP    320          // E padded to multiple of 32
#define G3    768          // 3*U
#define NTOT  1536         // both directions concatenated
#define C_DIM 20
#define BT    (B_SZ*T_LEN)

__device__ __forceinline__ float bf2f(u16 h){ return __uint_as_float(((u32)h)<<16); }
__device__ __forceinline__ u16 f2bf(float f){
  u32 u = __float_as_uint(f);
  u32 r = (u + 0x7FFFu + ((u>>16)&1u)) >> 16;   // RNE
  return (u16)r;
}

// ------------- embedding gather f32 -> bf16, K-pad (300 -> 320, zeros) --------
__global__ void embed_pad(const int* __restrict__ x, const float* __restrict__ emb,
                          u16* __restrict__ e){
  int idx = blockIdx.x*256 + threadIdx.x;
  if(idx >= BT*EP) return;
  int row = idx / EP, col = idx - row*EP;
  u16 v = 0;
  if(col < E_DIM) v = f2bf(emb[(size_t)x[row]*E_DIM + col]);
  e[idx] = v;
}

// ------ transpose + concat two f32 [K,768] sources -> bf16 dst[N][Kp] ---------
__global__ void transpose_cc(const float* __restrict__ A, const float* __restrict__ Bm,
                             u16* __restrict__ dst, int K, int Kp, int N){
  int idx = blockIdx.x*256 + threadIdx.x;
  if(idx >= N*Kp) return;
  int n = idx / Kp, k = idx - n*Kp;
  u16 v = 0;
  if(k < K){
    const float* s = (n < G3) ? A : Bm;
    int nn = (n < G3) ? n : n - G3;
    v = f2bf(s[(size_t)k*G3 + nn]);
  }
  dst[idx] = v;
}

// ---- prepack the 12 global-resident rk frags per (dir,wave) in scan order ----
// rkq[dir][w][j][lane][8]; j<6: (gs=j,kt=0), j>=6: (gs=j-6,kt=2)
__global__ void pack_rk(const u16* __restrict__ rkbase, u16* __restrict__ rkq){
  int idx = blockIdx.x*256 + threadIdx.x;
  if(idx >= 2*8*12*64) return;
  int dir = idx/6144, r = idx%6144;
  int w2 = r/768, r2 = r%768, j = r2>>6, lane = r2&63;
  int gs = (j<6)? j : j-6, kt = (j<6)? 0 : 2;
  int n  = (gs>>1)*256 + w2*32 + (gs&1)*16 + (lane&15);
  *(s8v*)(rkq + (size_t)idx*8) =
    *(const s8v*)(rkbase + (size_t)dir*G3*U_DIM + (size_t)n*U_DIM + kt*32 + (lane>>4)*8);
}

// ------- GEMM: xq[dir][bg][t][g][tid][8] = A[M,Kp] @ BT^T + bias (bf16) -------
__global__ __launch_bounds__(256) void gemm_bt(
    const u16* __restrict__ A, const u16* __restrict__ BT_, u16* __restrict__ Cq,
    int Kp, const float* __restrict__ biasA, const float* __restrict__ biasB)
{
  __shared__ u16 Al[128][40];   // +8 pad breaks bank collisions
  __shared__ u16 Bl[128][40];
  int tid = threadIdx.x;
  int w = tid>>6, l = tid&63, lc = l&15, quad = l>>4;
  int wm = w>>1, wn = w&1;
  int mb = blockIdx.y*128, nb = blockIdx.x*128;

  f4v acc[4][4];
  #pragma unroll
  for(int i=0;i<4;i++)
    #pragma unroll
    for(int j=0;j<4;j++) acc[i][j] = (f4v){0.f,0.f,0.f,0.f};

  int nk = Kp >> 5;
  for(int kt=0; kt<nk; kt++){
    __syncthreads();
    {
      int c0 = tid, c1 = tid + 256;
      int r0 = c0>>2, k80 = c0&3;
      int r1 = c1>>2, k81 = c1&3;
      *(s8v*)&Al[r0][k80*8] = *(const s8v*)(A   + (size_t)(mb+r0)*Kp + kt*32 + k80*8);
      *(s8v*)&Al[r1][k81*8] = *(const s8v*)(A   + (size_t)(mb+r1)*Kp + kt*32 + k81*8);
      *(s8v*)&Bl[r0][k80*8] = *(const s8v*)(BT_ + (size_t)(nb+r0)*Kp + kt*32 + k80*8);
      *(s8v*)&Bl[r1][k81*8] = *(const s8v*)(BT_ + (size_t)(nb+r1)*Kp + kt*32 + k81*8);
    }
    __syncthreads();
    s8v af[4], bf[4];
    #pragma unroll
    for(int i=0;i<4;i++) af[i] = *(const s8v*)&Al[wm*64 + i*16 + lc][quad*8];
    #pragma unroll
    for(int j=0;j<4;j++) bf[j] = *(const s8v*)&Bl[wn*64 + j*16 + lc][quad*8];
    #pragma unroll
    for(int i=0;i<4;i++)
      #pragma unroll
      for(int j=0;j<4;j++)
        acc[i][j] = __builtin_amdgcn_mfma_f32_16x16x32_bf16(af[i], bf[j], acc[i][j],0,0,0);
  }

  // permuted epilogue: row = b*512 + t (tile spans one b); col -> (dir,g,u)
  int b  = mb >> 9;
  int bg = b >> 4, m = b & 15, quad_s = m >> 2, r_s = m & 3;
  int tb = (mb & 511) + wm*64;
  #pragma unroll
  for(int j=0;j<4;j++){
    int col = nb + wn*64 + j*16 + lc;
    float bias = (col < G3) ? biasA[col] : biasB[col - G3];
    int dir = (col >= G3) ? 1 : 0;
    int c7  = col - dir*G3;
    int g   = c7 >> 8, u = c7 & 255;
    int w_s = u>>5, rem = u&31, s = rem>>4, lc_s = rem&15;
    size_t cb = ((size_t)(dir*4+bg)*512*3 + g)*4096
              + (size_t)((w_s*64 + quad_s*16 + lc_s)*8 + s*4 + r_s);
    #pragma unroll
    for(int i=0;i<4;i++){
      #pragma unroll
      for(int r=0;r<4;r++){
        int t = tb + i*16 + quad*4 + r;
        Cq[cb + (size_t)t*12288] = f2bf(acc[i][j][r] + bias);
      }
    }
  }
}

// ---------------- GRU scan: AGPR + global-L2 + small-LDS residency (v5) -------
// 8 blocks (dir = blk&1, bg = blk>>1, M=16). 512 threads = 8 waves; wave w owns
// u in [32w,32w+32) -> 96 gate-cols. rk residency per wave (48 frags):
//   AGPR (128/128): kt3..7 all gs -> a0..a119; kt1 gs0/gs1 -> a120..127.
//   GLOBAL (L2-resident, prepacked): kt0 all gs + kt2 all gs (12 frags),
//     loads issued in the loop TAIL before the lgkmcnt-only barrier -> a full
//     step of latency hiding (vmcnt survives LBAR). Bases asm-pinned so LICM
//     can't hoist them.
//   LDS: kt1 gs2..5 (4 frags). LDS pipe/step: 64 areg + 32 bl b128 (was 192).

#define INITF(F,A0,A1,A2,A3) { \
  i4v t = *(const i4v*)(rkd + (size_t)((F/10)*256 + w*32 + ((F/5)&1)*16 + lc)*U_DIM \
                            + ((F%5)+3)*32 + quad*8); \
  asm volatile("v_accvgpr_write_b32 a" #A0 ", %0\n\t" \
               "v_accvgpr_write_b32 a" #A1 ", %1\n\t" \
               "v_accvgpr_write_b32 a" #A2 ", %2\n\t" \
               "v_accvgpr_write_b32 a" #A3 ", %3" \
               :: "v"(t[0]), "v"(t[1]), "v"(t[2]), "v"(t[3]) \
               : "a" #A0, "a" #A1, "a" #A2, "a" #A3); }

#define INITX(NOFF,KT,A0,A1,A2,A3) { \
  i4v t = *(const i4v*)(rkd + (size_t)(NOFF)*U_DIM + (KT)*32 + quad*8); \
  asm volatile("v_accvgpr_write_b32 a" #A0 ", %0\n\t" \
               "v_accvgpr_write_b32 a" #A1 ", %1\n\t" \
               "v_accvgpr_write_b32 a" #A2 ", %2\n\t" \
               "v_accvgpr_write_b32 a" #A3 ", %3" \
               :: "v"(t[0]), "v"(t[1]), "v"(t[2]), "v"(t[3]) \
               : "a" #A0, "a" #A1, "a" #A2, "a" #A3); }

#define MFZ(ACC,AF,BF) \
  asm("v_mfma_f32_16x16x32_bf16 %0, %1, %2, 0" : "=&v"(ACC) : "v"(AF), "v"(BF))
#define MFA(ACC,AF,R0,R3) \
  asm("v_mfma_f32_16x16x32_bf16 %0, %1, a[" #R0 ":" #R3 "], %0" \
      : "+v"(ACC) : "v"(AF))
#define MFV(ACC,AF,BF) \
  asm("v_mfma_f32_16x16x32_bf16 %0, %1, %2, %0" : "+v"(ACC) : "v"(AF), "v"(BF))
#define MFE(ACC,AF,BF) \
  asm("v_mfma_f32_16x16x32_bf16 %0, %1, %2, %0\n\ts_nop 7\n\ts_nop 7" \
      : "+v"(ACC) : "v"(AF), "v"(BF))

#define AFENCE asm volatile("" ::: \
  "a0","a1","a2","a3","a4","a5","a6","a7","a8","a9", \
  "a10","a11","a12","a13","a14","a15","a16","a17","a18","a19", \
  "a20","a21","a22","a23","a24","a25","a26","a27","a28","a29", \
  "a30","a31","a32","a33","a34","a35","a36","a37","a38","a39", \
  "a40","a41","a42","a43","a44","a45","a46","a47","a48","a49", \
  "a50","a51","a52","a53","a54","a55","a56","a57","a58","a59", \
  "a60","a61","a62","a63","a64","a65","a66","a67","a68","a69", \
  "a70","a71","a72","a73","a74","a75","a76","a77","a78","a79", \
  "a80","a81","a82","a83","a84","a85","a86","a87","a88","a89", \
  "a90","a91","a92","a93","a94","a95","a96","a97","a98","a99", \
  "a100","a101","a102","a103","a104","a105","a106","a107","a108","a109", \
  "a110","a111","a112","a113","a114","a115","a116","a117","a118","a119", \
  "a120","a121","a122","a123","a124","a125","a126","a127")

#define LBAR asm volatile("s_waitcnt lgkmcnt(0)\n\ts_barrier" ::: "memory")

template<int MODE>
__global__ __launch_bounds__(512,2) void gru_scan3(
    const u16* __restrict__ xq,    // packed preacts (see gemm_bt)
    const u16* __restrict__ rkT,   // [2][768][256] bf16 transposed recurrent kernels
    const u16* __restrict__ rkq,   // prepacked global frags [2][8][12][64][8]
    const float* __restrict__ bF, const float* __restrict__ bB,  // b[2][768] f32
    u16* __restrict__ h1out,       // MODE 0: [BT,512]
    float* __restrict__ h2out)     // MODE 1: [64,512] final states
{
  int dir = blockIdx.x & 1, bg = blockIdx.x >> 1;
  int b0 = bg*16;
  int tid = threadIdx.x;
  int w = tid>>6, l = tid&63, lc = l&15, quad = l>>4;

  __shared__ u16 rklW[8*4*64*8];   // wave-private kt1 gs2..5 frags (32,768 B)
  __shared__ u16 hb[2][16][264];   // double-buffered h (16,896 B)
  for(int i=tid; i<2*16*264; i+=512) ((u16*)hb)[i] = 0;

  const u16*   rkd  = rkT + (size_t)dir*G3*U_DIM;
  const float* bias = (dir ? bB : bF) + G3;   // row 1 = recurrent bias

  // stage LDS frags: 4 per wave (gs=2..5, kt=1), lane-contiguous 16B
  for(int idx=tid; idx<8*4*64; idx+=512){
    int w2 = idx>>8, r = idx&255, fi = r>>6, lane = r&63;
    int gs = fi+2;
    int n = (gs>>1)*256 + w2*32 + (gs&1)*16 + (lane&15);
    *(s8v*)&rklW[(size_t)idx*8] =
      *(const s8v*)(rkd + (size_t)n*U_DIM + 32 + (lane>>4)*8);
  }

  // AGPR frags: kt3..7 -> a0..a119
  INITF(0,0,1,2,3)       INITF(1,4,5,6,7)       INITF(2,8,9,10,11)
  INITF(3,12,13,14,15)   INITF(4,16,17,18,19)   INITF(5,20,21,22,23)
  INITF(6,24,25,26,27)   INITF(7,28,29,30,31)   INITF(8,32,33,34,35)
  INITF(9,36,37,38,39)   INITF(10,40,41,42,43)  INITF(11,44,45,46,47)
  INITF(12,48,49,50,51)  INITF(13,52,53,54,55)  INITF(14,56,57,58,59)
  INITF(15,60,61,62,63)  INITF(16,64,65,66,67)  INITF(17,68,69,70,71)
  INITF(18,72,73,74,75)  INITF(19,76,77,78,79)  INITF(20,80,81,82,83)
  INITF(21,84,85,86,87)  INITF(22,88,89,90,91)  INITF(23,92,93,94,95)
  INITF(24,96,97,98,99)  INITF(25,100,101,102,103) INITF(26,104,105,106,107)
  INITF(27,108,109,110,111) INITF(28,112,113,114,115) INITF(29,116,117,118,119)
  INITX(w*32 + lc,      1, 120,121,122,123)
  INITX(w*32 + 16 + lc, 1, 124,125,126,127)

  float bgf[3][2];
  #pragma unroll
  for(int g=0;g<3;g++)
    #pragma unroll
    for(int s=0;s<2;s++)
      bgf[g][s] = bias[g*256 + w*32 + s*16 + lc];

  int t0 = dir ? (T_LEN-1) : 0;
  long qstride = dir ? -12288L : 12288L;             // xq u16-elems per step
  long hstride = dir ? -(long)(2*U_DIM) : (long)(2*U_DIM);
  const u16* xqp = xq + ((size_t)(dir*4+bg)*512 + t0)*12288 + (size_t)tid*8;
  u16* hop[4];
  #pragma unroll
  for(int r=0;r<4;r++){
    int m = quad*4 + r;
    hop[r] = (MODE==0) ? (h1out + ((size_t)(b0+m)*T_LEN + t0)*(2*U_DIM) + dir*U_DIM + w*32 + lc)
                       : nullptr;
  }

  // global-frag base pointers (per lane; imm offsets 0..3072 B per base)
  const u16* gb0 = rkq + (((size_t)(dir*8 + w)*12)*64 + l)*8;
  const u16* gb4 = gb0 + 4*512;
  const u16* gb8 = gb0 + 8*512;

  float hpc[2][4];   // carried h_prev (own cells), f32
  #pragma unroll
  for(int s=0;s<2;s++)
    #pragma unroll
    for(int r=0;r<4;r++) hpc[s][r] = 0.f;

  s8v G0[6], G2[6];
  // prologue issue (step 0)
  #pragma unroll
  for(int j=0;j<4;j++) G0[j] = *(const s8v*)(gb0 + j*512);
  G0[4] = *(const s8v*)(gb4);       G0[5] = *(const s8v*)(gb4 + 512);
  G2[0] = *(const s8v*)(gb4 + 1024); G2[1] = *(const s8v*)(gb4 + 1536);
  #pragma unroll
  for(int j=0;j<4;j++) G2[j+2] = *(const s8v*)(gb8 + j*512);

  __syncthreads();

  int cur = 0;
  for(int step=0; step<T_LEN; step++){
    AFENCE;
    // pin bases: redefine each iteration so the tail loads can't be hoisted
    asm volatile("" : "+v"(gb0), "+v"(gb4), "+v"(gb8));

    // packed xw preacts: 3 x dwordx4 (gate g at +g*4096 u16)
    i4v c0 = *(const i4v*)(xqp);
    i4v c1 = *(const i4v*)(xqp + 4096);
    i4v c2 = *(const i4v*)(xqp + 8192);

    // h(t) reads, first half (kt0..2 A-frags)
    s8v aA[3];
    #pragma unroll
    for(int kt=0;kt<3;kt++) aA[kt] = *(const s8v*)&hb[cur][lc][kt*32 + quad*8];

    f4v acc[3][2];
    // kt0: global G0 (inline C=0)
    MFZ(acc[0][0],aA[0],G0[0]);  MFZ(acc[0][1],aA[0],G0[1]);
    MFZ(acc[1][0],aA[0],G0[2]);  MFZ(acc[1][1],aA[0],G0[3]);
    MFZ(acc[2][0],aA[0],G0[4]);  MFZ(acc[2][1],aA[0],G0[5]);
    // kt1: gs0/gs1 AGPR, gs2..5 LDS
    {
      s8v bl[4];
      #pragma unroll
      for(int i=0;i<4;i++)
        bl[i] = *(const s8v*)&rklW[(size_t)((w*4 + i)*64 + l)*8];
      MFA(acc[0][0],aA[1],120,123);  MFA(acc[0][1],aA[1],124,127);
      MFV(acc[1][0],aA[1],bl[0]);    MFV(acc[1][1],aA[1],bl[1]);
      MFV(acc[2][0],aA[1],bl[2]);    MFV(acc[2][1],aA[1],bl[3]);
    }
    // h(t) reads, second half (kt3..7)
    s8v aB[5];
    #pragma unroll
    for(int kt=0;kt<5;kt++) aB[kt] = *(const s8v*)&hb[cur][lc][(kt+3)*32 + quad*8];
    MFA(acc[0][0],aB[0],0,3);    MFA(acc[0][1],aB[0],20,23);
    MFA(acc[1][0],aB[0],40,43);  MFA(acc[1][1],aB[0],60,63);
    MFA(acc[2][0],aB[0],80,83);  MFA(acc[2][1],aB[0],100,103);
    MFA(acc[0][0],aB[1],4,7);    MFA(acc[0][1],aB[1],24,27);
    MFA(acc[1][0],aB[1],44,47);  MFA(acc[1][1],aB[1],64,67);
    MFA(acc[2][0],aB[1],84,87);  MFA(acc[2][1],aB[1],104,107);
    MFA(acc[0][0],aB[2],8,11);   MFA(acc[0][1],aB[2],28,31);
    MFA(acc[1][0],aB[2],48,51);  MFA(acc[1][1],aB[2],68,71);
    MFA(acc[2][0],aB[2],88,91);  MFA(acc[2][1],aB[2],108,111);
    MFA(acc[0][0],aB[3],12,15);  MFA(acc[0][1],aB[3],32,35);
    MFA(acc[1][0],aB[3],52,55);  MFA(acc[1][1],aB[3],72,75);
    MFA(acc[2][0],aB[3],92,95);  MFA(acc[2][1],aB[3],112,115);
    MFA(acc[0][0],aB[4],16,19);  MFA(acc[0][1],aB[4],36,39);
    MFA(acc[1][0],aB[4],56,59);  MFA(acc[1][1],aB[4],76,79);
    MFA(acc[2][0],aB[4],96,99);  MFA(acc[2][1],aB[4],116,119);
    // kt2 last: global G2 (trailing drain nops)
    MFE(acc[0][0],aA[2],G2[0]);  MFE(acc[0][1],aA[2],G2[1]);
    MFE(acc[1][0],aA[2],G2[2]);  MFE(acc[1][1],aA[2],G2[3]);
    MFE(acc[2][0],aA[2],G2[4]);  MFE(acc[2][1],aA[2],G2[5]);

    AFENCE;

    // gates + state update; xw inputs unpacked from c0/c1/c2
    #pragma unroll
    for(int s=0;s<2;s++){
      int u = w*32 + s*16 + lc;
      #pragma unroll
      for(int r=0;r<4;r++){
        int m = quad*4 + r;
        int k = s*4 + r, ki = k>>1;
        float xz, xr, xh;
        if(k & 1){
          xz = __uint_as_float(((u32)c0[ki]) & 0xffff0000u);
          xr = __uint_as_float(((u32)c1[ki]) & 0xffff0000u);
          xh = __uint_as_float(((u32)c2[ki]) & 0xffff0000u);
        } else {
          xz = __uint_as_float(((u32)c0[ki]) << 16);
          xr = __uint_as_float(((u32)c1[ki]) << 16);
          xh = __uint_as_float(((u32)c2[ki]) << 16);
        }
        float zf = acc[0][s][r] + bgf[0][s] + xz;
        float rf = acc[1][s][r] + bgf[1][s] + xr;
        float rh = acc[2][s][r] + bgf[2][s];
        zf = __builtin_amdgcn_rcpf(1.f + __expf(-zf));
        rf = __builtin_amdgcn_rcpf(1.f + __expf(-rf));
        float hc = xh + rf*rh;
        float e2 = __expf(2.f*hc);
        float th = 1.f - 2.f*__builtin_amdgcn_rcpf(e2 + 1.f);
        float hn = th + zf*(hpc[s][r] - th);
        hpc[s][r] = hn;
        u16 hbf = f2bf(hn);
        hb[cur^1][m][u] = hbf;
        if(MODE == 0)
          hop[r][s*16] = hbf;
        else if(step == T_LEN-1)
          h2out[(size_t)(b0+m)*(2*U_DIM) + dir*U_DIM + u] = hn;
      }
    }

    xqp += qstride;
    if(MODE==0){
      #pragma unroll
      for(int r=0;r<4;r++) hop[r] += hstride;
    }

    // tail: issue next step's global frags (vmcnt survives the LDS-only barrier)
    #pragma unroll
    for(int j=0;j<4;j++) G0[j] = *(const s8v*)(gb0 + j*512);
    G0[4] = *(const s8v*)(gb4);       G0[5] = *(const s8v*)(gb4 + 512);
    G2[0] = *(const s8v*)(gb4 + 1024); G2[1] = *(const s8v*)(gb4 + 1536);
    #pragma unroll
    for(int j=0;j<4;j++) G2[j+2] = *(const s8v*)(gb8 + j*512);

    LBAR;
    cur ^= 1;
  }
}

// ---------------- final projection + softmax (f32 output) ---------------------
__global__ void out_softmax(const float* __restrict__ h2, const float* __restrict__ wout,
                            const float* __restrict__ bout, float* __restrict__ out)
{
  __shared__ float lg[C_DIM];
  int b = blockIdx.x, l = threadIdx.x;   // 64 threads = 1 wave
  float acc[C_DIM];
  #pragma unroll
  for(int c=0;c<C_DIM;c++) acc[c] = 0.f;
  for(int k=l; k<2*U_DIM; k+=64){
    float hv = h2[b*2*U_DIM + k];
    #pragma unroll
    for(int c=0;c<C_DIM;c++) acc[c] += hv * wout[k*C_DIM + c];
  }
  #pragma unroll
  for(int c=0;c<C_DIM;c++){
    float v = acc[c];
    for(int off=32; off; off>>=1) v += __shfl_down(v, off);
    if(l==0) lg[c] = v + bout[c];
  }
  __syncthreads();
  if(l==0){
    float mx = lg[0];
    for(int c=1;c<C_DIM;c++) mx = fmaxf(mx, lg[c]);
    float sum = 0.f, ex[C_DIM];
    for(int c=0;c<C_DIM;c++){ ex[c] = __expf(lg[c]-mx); sum += ex[c]; }
    for(int c=0;c<C_DIM;c++) out[b*C_DIM + c] = ex[c]/sum;
  }
}

extern "C" void kernel_launch(void* const* d_in, const int* in_sizes, int n_in,
                              void* d_out, int out_size, void* d_ws, size_t ws_size,
                              hipStream_t stream)
{
  const int*   x    = (const int*)d_in[0];
  const float* emb  = (const float*)d_in[1];
  const float* k1f  = (const float*)d_in[2];
  const float* rk1f = (const float*)d_in[3];
  const float* b1f  = (const float*)d_in[4];
  const float* k1b  = (const float*)d_in[5];
  const float* rk1b = (const float*)d_in[6];
  const float* b1b  = (const float*)d_in[7];
  const float* k2f  = (const float*)d_in[8];
  const float* rk2f = (const float*)d_in[9];
  const float* b2f  = (const float*)d_in[10];
  const float* k2b  = (const float*)d_in[11];
  const float* rk2b = (const float*)d_in[12];
  const float* b2b  = (const float*)d_in[13];
  const float* wout = (const float*)d_in[14];
  const float* bout = (const float*)d_in[15];

  char* ws = (char*)d_ws;
  u16*  k1t   = (u16*)(ws);                       // 983,040 B     [1536,320]
  u16*  rkq   = (u16*)(ws);                       // 196,608 B     (aliases k1t; used after gemm1)
  u16*  k2t   = (u16*)(ws + 983040);              // 1,572,864 B   [1536,512]
  u16*  rkt   = (u16*)(ws + 2555904);             // 1,572,864 B   4x[768,256]
  float* h2   = (float*)(ws + 4128768);           // 131,072 B     [64,512]
  u16*  h1    = (u16*)(ws + 4259840);             // 33,554,432 B  [BT,512]
  u16*  e_pad = (u16*)(ws + 4259840);             // (alias h1)
  u16*  xq    = (u16*)(ws + 37814272);            // 100,663,296 B packed preacts

  transpose_cc<<<(NTOT*EP +255)/256,256,0,stream>>>(k1f, k1b, k1t, E_DIM, EP, NTOT);
  transpose_cc<<<(NTOT*512+255)/256,256,0,stream>>>(k2f, k2b, k2t, 512, 512, NTOT);
  transpose_cc<<<(G3*U_DIM+255)/256,256,0,stream>>>(rk1f, rk1f, rkt,                U_DIM, U_DIM, G3);
  transpose_cc<<<(G3*U_DIM+255)/256,256,0,stream>>>(rk1b, rk1b, rkt + 1*G3*U_DIM,   U_DIM, U_DIM, G3);
  transpose_cc<<<(G3*U_DIM+255)/256,256,0,stream>>>(rk2f, rk2f, rkt + 2*G3*U_DIM,   U_DIM, U_DIM, G3);
  transpose_cc<<<(G3*U_DIM+255)/256,256,0,stream>>>(rk2b, rk2b, rkt + 3*G3*U_DIM,   U_DIM, U_DIM, G3);

  embed_pad<<<(BT*EP)/256,256,0,stream>>>(x, emb, e_pad);

  // layer 1: xq = pack(e @ K1 + b0) ; pack rk frags ; scan -> h1
  gemm_bt<<<dim3(12,256),256,0,stream>>>(e_pad, k1t, xq, EP, b1f, b1b);
  pack_rk<<<48,256,0,stream>>>(rkt, rkq);
  gru_scan3<0><<<8,512,0,stream>>>(xq, rkt, rkq, b1f, b1b, h1, nullptr);

  // layer 2: xq = pack(h1 @ K2 + b0) ; pack rk frags ; scan -> h2
  gemm_bt<<<dim3(12,256),256,0,stream>>>(h1, k2t, xq, 512, b2f, b2b);
  pack_rk<<<48,256,0,stream>>>(rkt + 2*G3*U_DIM, rkq);
  gru_scan3<1><<<8,512,0,stream>>>(xq, rkt + 2*G3*U_DIM, rkq, b2f, b2b, nullptr, h2);

  out_softmax<<<64,64,0,stream>>>(h2, wout, bout, (float*)d_out);
}

// Round 15
// 2105.287 us; speedup vs baseline: 1.1193x; 1.1193x over previous
//
#include <hip/hip_runtime.h>

typedef unsigned short u16;
typedef unsigned int   u32;
typedef unsigned long long u64;
typedef __attribute__((ext_vector_type(8))) short s8v;   // 8 x bf16 bits (4 VGPRs)
typedef __attribute__((ext_vector_type(4))) float f4v;   // MFMA accumulator
typedef __attribute__((ext_vector_type(4))) int   i4v;   // 4 VGPRs (generic 16B)

#define B_SZ  64
#define T_LEN 512
#define U_DIM 256
#define E_DIM 300
#define EP    320          // E padded to multiple of 32
#define G3    768          // 3*U
#define NTOT  1536         // both directions concatenated
#define C_DIM 20
#define BT    (B_SZ*T_LEN)

__device__ __forceinline__ float bf2f(u16 h){ return __uint_as_float(((u32)h)<<16); }
__device__ __forceinline__ u16 f2bf(float f){
  u32 u = __float_as_uint(f);
  u32 r = (u + 0x7FFFu + ((u>>16)&1u)) >> 16;   // RNE
  return (u16)r;
}

// ------------- embedding gather f32 -> bf16, K-pad (300 -> 320, zeros) --------
__global__ void embed_pad(const int* __restrict__ x, const float* __restrict__ emb,
                          u16* __restrict__ e){
  int idx = blockIdx.x*256 + threadIdx.x;
  if(idx >= BT*EP) return;
  int row = idx / EP, col = idx - row*EP;
  u16 v = 0;
  if(col < E_DIM) v = f2bf(emb[(size_t)x[row]*E_DIM + col]);
  e[idx] = v;
}

// ------ transpose + concat two f32 [K,768] sources -> bf16 dst[N][Kp] ---------
__global__ void transpose_cc(const float* __restrict__ A, const float* __restrict__ Bm,
                             u16* __restrict__ dst, int K, int Kp, int N){
  int idx = blockIdx.x*256 + threadIdx.x;
  if(idx >= N*Kp) return;
  int n = idx / Kp, k = idx - n*Kp;
  u16 v = 0;
  if(k < K){
    const float* s = (n < G3) ? A : Bm;
    int nn = (n < G3) ? n : n - G3;
    v = f2bf(s[(size_t)k*G3 + nn]);
  }
  dst[idx] = v;
}

// ------- GEMM: xq[dir][bg][t][g][tid][8] = A @ BT^T + bias (bf16, packed) -----
// Interleaved-M tile: 128 rows = 4 batches x 32 t, row = t_loc*4 + b_loc, so
// the 4 MFMA acc regs (C-rows quad*4+r) are 4 batches at one t = the scan
// chunk's contiguous r elements -> ONE u64 store per (i,j) (was 64 x 2B scatter).
__global__ __launch_bounds__(256) void gemm_bt(
    const u16* __restrict__ A, const u16* __restrict__ BT_, u16* __restrict__ Cq,
    int Kp, const float* __restrict__ biasA, const float* __restrict__ biasB)
{
  __shared__ u16 Al[128][40];   // +8 pad breaks bank collisions
  __shared__ u16 Bl[128][40];
  int tid = threadIdx.x;
  int w = tid>>6, l = tid&63, lc = l&15, quad = l>>4;
  int wm = w>>1, wn = w&1;
  int nb = blockIdx.x*128;
  int bg4 = blockIdx.y >> 4, tg = blockIdx.y & 15;
  int b0r = bg4*4, tb0 = tg*32;

  f4v acc[4][4];
  #pragma unroll
  for(int i=0;i<4;i++)
    #pragma unroll
    for(int j=0;j<4;j++) acc[i][j] = (f4v){0.f,0.f,0.f,0.f};

  int nk = Kp >> 5;
  for(int kt=0; kt<nk; kt++){
    __syncthreads();
    {
      int c0 = tid, c1 = tid + 256;
      int r0 = c0>>2, k80 = c0&3;
      int r1 = c1>>2, k81 = c1&3;
      size_t ga0 = ((size_t)(b0r + (r0&3))*T_LEN + tb0 + (r0>>2))*Kp;
      size_t ga1 = ((size_t)(b0r + (r1&3))*T_LEN + tb0 + (r1>>2))*Kp;
      *(s8v*)&Al[r0][k80*8] = *(const s8v*)(A + ga0 + kt*32 + k80*8);
      *(s8v*)&Al[r1][k81*8] = *(const s8v*)(A + ga1 + kt*32 + k81*8);
      *(s8v*)&Bl[r0][k80*8] = *(const s8v*)(BT_ + (size_t)(nb+r0)*Kp + kt*32 + k80*8);
      *(s8v*)&Bl[r1][k81*8] = *(const s8v*)(BT_ + (size_t)(nb+r1)*Kp + kt*32 + k81*8);
    }
    __syncthreads();
    s8v af[4], bf[4];
    #pragma unroll
    for(int i=0;i<4;i++) af[i] = *(const s8v*)&Al[wm*64 + i*16 + lc][quad*8];
    #pragma unroll
    for(int j=0;j<4;j++) bf[j] = *(const s8v*)&Bl[wn*64 + j*16 + lc][quad*8];
    #pragma unroll
    for(int i=0;i<4;i++)
      #pragma unroll
      for(int j=0;j<4;j++)
        acc[i][j] = __builtin_amdgcn_mfma_f32_16x16x32_bf16(af[i], bf[j], acc[i][j],0,0,0);
  }

  // packed epilogue: one 8-B store per (i,j)
  #pragma unroll
  for(int j=0;j<4;j++){
    int col = nb + wn*64 + j*16 + lc;
    float bias = (col < G3) ? biasA[col] : biasB[col - G3];
    int dir = (col >= G3) ? 1 : 0;
    int c7  = col - dir*G3;
    int g   = c7 >> 8, u = c7 & 255;
    int w_s = u>>5, s = (u>>4)&1, lc_s = u&15;
    size_t db = ((size_t)(dir*4 + (bg4>>2))*512)*12288 + (size_t)g*4096
              + (size_t)((w_s*64 + (bg4&3)*16 + lc_s)*8 + s*4);
    #pragma unroll
    for(int i=0;i<4;i++){
      int t = tb0 + wm*16 + i*4 + quad;
      u16 p0 = f2bf(acc[i][j][0] + bias);
      u16 p1 = f2bf(acc[i][j][1] + bias);
      u16 p2 = f2bf(acc[i][j][2] + bias);
      u16 p3 = f2bf(acc[i][j][3] + bias);
      *(u64*)(Cq + db + (size_t)t*12288) =
        (u64)p0 | ((u64)p1<<16) | ((u64)p2<<32) | ((u64)p3<<48);
    }
  }
}

// ---------------- GRU scan: hard-coded AGPR + LDS residency (R13 verbatim) ----
#define INITF(F,A0,A1,A2,A3) { \
  i4v t = *(const i4v*)(rkd + (size_t)((F/10)*256 + w*32 + ((F/5)&1)*16 + lc)*U_DIM \
                            + ((F%5)+3)*32 + quad*8); \
  asm volatile("v_accvgpr_write_b32 a" #A0 ", %0\n\t" \
               "v_accvgpr_write_b32 a" #A1 ", %1\n\t" \
               "v_accvgpr_write_b32 a" #A2 ", %2\n\t" \
               "v_accvgpr_write_b32 a" #A3 ", %3" \
               :: "v"(t[0]), "v"(t[1]), "v"(t[2]), "v"(t[3]) \
               : "a" #A0, "a" #A1, "a" #A2, "a" #A3); }

#define INITX(NOFF,KT,A0,A1,A2,A3) { \
  i4v t = *(const i4v*)(rkd + (size_t)(NOFF)*U_DIM + (KT)*32 + quad*8); \
  asm volatile("v_accvgpr_write_b32 a" #A0 ", %0\n\t" \
               "v_accvgpr_write_b32 a" #A1 ", %1\n\t" \
               "v_accvgpr_write_b32 a" #A2 ", %2\n\t" \
               "v_accvgpr_write_b32 a" #A3 ", %3" \
               :: "v"(t[0]), "v"(t[1]), "v"(t[2]), "v"(t[3]) \
               : "a" #A0, "a" #A1, "a" #A2, "a" #A3); }

#define MFZ(ACC,AF,BF) \
  asm("v_mfma_f32_16x16x32_bf16 %0, %1, %2, 0" : "=&v"(ACC) : "v"(AF), "v"(BF))
#define MFA(ACC,AF,R0,R3) \
  asm("v_mfma_f32_16x16x32_bf16 %0, %1, a[" #R0 ":" #R3 "], %0" \
      : "+v"(ACC) : "v"(AF))
#define MFV(ACC,AF,BF) \
  asm("v_mfma_f32_16x16x32_bf16 %0, %1, %2, %0" : "+v"(ACC) : "v"(AF), "v"(BF))
#define MFAE(ACC,AF,R0,R3) \
  asm("v_mfma_f32_16x16x32_bf16 %0, %1, a[" #R0 ":" #R3 "], %0\n\ts_nop 7\n\ts_nop 7" \
      : "+v"(ACC) : "v"(AF))

#define AFENCE asm volatile("" ::: \
  "a0","a1","a2","a3","a4","a5","a6","a7","a8","a9", \
  "a10","a11","a12","a13","a14","a15","a16","a17","a18","a19", \
  "a20","a21","a22","a23","a24","a25","a26","a27","a28","a29", \
  "a30","a31","a32","a33","a34","a35","a36","a37","a38","a39", \
  "a40","a41","a42","a43","a44","a45","a46","a47","a48","a49", \
  "a50","a51","a52","a53","a54","a55","a56","a57","a58","a59", \
  "a60","a61","a62","a63","a64","a65","a66","a67","a68","a69", \
  "a70","a71","a72","a73","a74","a75","a76","a77","a78","a79", \
  "a80","a81","a82","a83","a84","a85","a86","a87","a88","a89", \
  "a90","a91","a92","a93","a94","a95","a96","a97","a98","a99", \
  "a100","a101","a102","a103","a104","a105","a106","a107","a108","a109", \
  "a110","a111","a112","a113","a114","a115","a116","a117","a118","a119", \
  "a120","a121","a122","a123","a124","a125","a126","a127")

#define LBAR asm volatile("s_waitcnt lgkmcnt(0)\n\ts_barrier" ::: "memory")

__device__ __forceinline__ int lfi(int gs, int kt){
  return (gs < 2) ? (gs*2 + (kt ? 1 : 0)) : (4 + (gs-2)*3 + kt);
}

template<int MODE>
__global__ __launch_bounds__(512,2) void gru_scan3(
    const u16* __restrict__ xq,    // packed preacts (see gemm_bt)
    const u16* __restrict__ rkT,   // [2][768][256] bf16 transposed recurrent kernels
    const float* __restrict__ bF, const float* __restrict__ bB,  // b[2][768] f32
    u16* __restrict__ h1out,       // MODE 0: [BT,512]
    float* __restrict__ h2out)     // MODE 1: [64,512] final states
{
  int dir = blockIdx.x & 1, bg = blockIdx.x >> 1;
  int b0 = bg*16;
  int tid = threadIdx.x;
  int w = tid>>6, l = tid&63, lc = l&15, quad = l>>4;

  __shared__ u16 rklW[8*16*64*8];  // wave-private B-frags, 16/wave (131,072 B)
  __shared__ u16 hb[2][16][264];   // double-buffered h (16,896 B)
  for(int i=tid; i<2*16*264; i+=512) ((u16*)hb)[i] = 0;

  const u16*   rkd  = rkT + (size_t)dir*G3*U_DIM;
  const float* bias = (dir ? bB : bF) + G3;   // row 1 = recurrent bias

  // stage LDS B-frags (16 per wave, lane-contiguous 16B)
  for(int idx=tid; idx<8*16*64; idx+=512){
    int w2 = idx>>10, r = idx&1023, fi = r>>6, lane = r&63;
    int gs, kt;
    if(fi < 4){ gs = fi>>1; kt = (fi&1)*2; }
    else      { int q = fi-4; gs = (q/3)+2; kt = q%3; }
    int n = (gs>>1)*256 + w2*32 + (gs&1)*16 + (lane&15);
    *(s8v*)&rklW[(size_t)idx*8] =
      *(const s8v*)(rkd + (size_t)n*U_DIM + kt*32 + (lane>>4)*8);
  }

  // AGPR frags: kt3..7 -> a0..a119
  INITF(0,0,1,2,3)       INITF(1,4,5,6,7)       INITF(2,8,9,10,11)
  INITF(3,12,13,14,15)   INITF(4,16,17,18,19)   INITF(5,20,21,22,23)
  INITF(6,24,25,26,27)   INITF(7,28,29,30,31)   INITF(8,32,33,34,35)
  INITF(9,36,37,38,39)   INITF(10,40,41,42,43)  INITF(11,44,45,46,47)
  INITF(12,48,49,50,51)  INITF(13,52,53,54,55)  INITF(14,56,57,58,59)
  INITF(15,60,61,62,63)  INITF(16,64,65,66,67)  INITF(17,68,69,70,71)
  INITF(18,72,73,74,75)  INITF(19,76,77,78,79)  INITF(20,80,81,82,83)
  INITF(21,84,85,86,87)  INITF(22,88,89,90,91)  INITF(23,92,93,94,95)
  INITF(24,96,97,98,99)  INITF(25,100,101,102,103) INITF(26,104,105,106,107)
  INITF(27,108,109,110,111) INITF(28,112,113,114,115) INITF(29,116,117,118,119)
  INITX(w*32 + lc,      1, 120,121,122,123)
  INITX(w*32 + 16 + lc, 1, 124,125,126,127)

  float bgf[3][2];
  #pragma unroll
  for(int g=0;g<3;g++)
    #pragma unroll
    for(int s=0;s<2;s++)
      bgf[g][s] = bias[g*256 + w*32 + s*16 + lc];

  int t0 = dir ? (T_LEN-1) : 0;
  long qstride = dir ? -12288L : 12288L;             // xq u16-elems per step
  long hstride = dir ? -(long)(2*U_DIM) : (long)(2*U_DIM);
  const u16* xqp = xq + ((size_t)(dir*4+bg)*512 + t0)*12288 + (size_t)tid*8;
  u16* hop[4];
  #pragma unroll
  for(int r=0;r<4;r++){
    int m = quad*4 + r;
    hop[r] = (MODE==0) ? (h1out + ((size_t)(b0+m)*T_LEN + t0)*(2*U_DIM) + dir*U_DIM + w*32 + lc)
                       : nullptr;
  }

  float hpc[2][4];   // carried h_prev (own cells), f32
  #pragma unroll
  for(int s=0;s<2;s++)
    #pragma unroll
    for(int r=0;r<4;r++) hpc[s][r] = 0.f;

  __syncthreads();

  int cur = 0;
  for(int step=0; step<T_LEN; step++){
    AFENCE;

    // packed xw preacts: 3 x dwordx4 (gate g at +g*4096 u16)
    i4v c0 = *(const i4v*)(xqp);
    i4v c1 = *(const i4v*)(xqp + 4096);
    i4v c2 = *(const i4v*)(xqp + 8192);

    // h(t) reads, first half (kt0..2)
    s8v aA[3];
    #pragma unroll
    for(int kt=0;kt<3;kt++) aA[kt] = *(const s8v*)&hb[cur][lc][kt*32 + quad*8];

    f4v acc[3][2];
    s8v bl[6];
    // kt0: all 6 from LDS (inline C=0)
    #pragma unroll
    for(int g=0;g<3;g++)
      #pragma unroll
      for(int s=0;s<2;s++)
        bl[g*2+s] = *(const s8v*)&rklW[(size_t)((w*16 + lfi(g*2+s,0))*64 + l)*8];
    MFZ(acc[0][0],aA[0],bl[0]);  MFZ(acc[0][1],aA[0],bl[1]);
    MFZ(acc[1][0],aA[0],bl[2]);  MFZ(acc[1][1],aA[0],bl[3]);
    MFZ(acc[2][0],aA[0],bl[4]);  MFZ(acc[2][1],aA[0],bl[5]);
    // kt1: gs0/gs1 from AGPR, gs2..5 from LDS
    #pragma unroll
    for(int g=1;g<3;g++)
      #pragma unroll
      for(int s=0;s<2;s++)
        bl[g*2+s] = *(const s8v*)&rklW[(size_t)((w*16 + lfi(g*2+s,1))*64 + l)*8];
    MFA(acc[0][0],aA[1],120,123);  MFA(acc[0][1],aA[1],124,127);
    MFV(acc[1][0],aA[1],bl[2]);    MFV(acc[1][1],aA[1],bl[3]);
    MFV(acc[2][0],aA[1],bl[4]);    MFV(acc[2][1],aA[1],bl[5]);
    // kt2: all 6 from LDS
    #pragma unroll
    for(int g=0;g<3;g++)
      #pragma unroll
      for(int s=0;s<2;s++)
        bl[g*2+s] = *(const s8v*)&rklW[(size_t)((w*16 + lfi(g*2+s,2))*64 + l)*8];
    MFV(acc[0][0],aA[2],bl[0]);  MFV(acc[0][1],aA[2],bl[1]);
    MFV(acc[1][0],aA[2],bl[2]);  MFV(acc[1][1],aA[2],bl[3]);
    MFV(acc[2][0],aA[2],bl[4]);  MFV(acc[2][1],aA[2],bl[5]);

    // h(t) reads, second half (kt3..7)
    s8v aB[5];
    #pragma unroll
    for(int kt=0;kt<5;kt++) aB[kt] = *(const s8v*)&hb[cur][lc][(kt+3)*32 + quad*8];
    MFA(acc[0][0],aB[0],0,3);    MFA(acc[0][1],aB[0],20,23);
    MFA(acc[1][0],aB[0],40,43);  MFA(acc[1][1],aB[0],60,63);
    MFA(acc[2][0],aB[0],80,83);  MFA(acc[2][1],aB[0],100,103);
    MFA(acc[0][0],aB[1],4,7);    MFA(acc[0][1],aB[1],24,27);
    MFA(acc[1][0],aB[1],44,47);  MFA(acc[1][1],aB[1],64,67);
    MFA(acc[2][0],aB[1],84,87);  MFA(acc[2][1],aB[1],104,107);
    MFA(acc[0][0],aB[2],8,11);   MFA(acc[0][1],aB[2],28,31);
    MFA(acc[1][0],aB[2],48,51);  MFA(acc[1][1],aB[2],68,71);
    MFA(acc[2][0],aB[2],88,91);  MFA(acc[2][1],aB[2],108,111);
    MFA(acc[0][0],aB[3],12,15);  MFA(acc[0][1],aB[3],32,35);
    MFA(acc[1][0],aB[3],52,55);  MFA(acc[1][1],aB[3],72,75);
    MFA(acc[2][0],aB[3],92,95);  MFA(acc[2][1],aB[3],112,115);
    MFAE(acc[0][0],aB[4],16,19);  MFAE(acc[0][1],aB[4],36,39);
    MFAE(acc[1][0],aB[4],56,59);  MFAE(acc[1][1],aB[4],76,79);
    MFAE(acc[2][0],aB[4],96,99);  MFAE(acc[2][1],aB[4],116,119);

    AFENCE;

    // gates + state update; xw inputs unpacked from c0/c1/c2
    #pragma unroll
    for(int s=0;s<2;s++){
      int u = w*32 + s*16 + lc;
      #pragma unroll
      for(int r=0;r<4;r++){
        int m = quad*4 + r;
        int k = s*4 + r, ki = k>>1;
        float xz, xr, xh;
        if(k & 1){
          xz = __uint_as_float(((u32)c0[ki]) & 0xffff0000u);
          xr = __uint_as_float(((u32)c1[ki]) & 0xffff0000u);
          xh = __uint_as_float(((u32)c2[ki]) & 0xffff0000u);
        } else {
          xz = __uint_as_float(((u32)c0[ki]) << 16);
          xr = __uint_as_float(((u32)c1[ki]) << 16);
          xh = __uint_as_float(((u32)c2[ki]) << 16);
        }
        float zf = acc[0][s][r] + bgf[0][s] + xz;
        float rf = acc[1][s][r] + bgf[1][s] + xr;
        float rh = acc[2][s][r] + bgf[2][s];
        zf = __builtin_amdgcn_rcpf(1.f + __expf(-zf));
        rf = __builtin_amdgcn_rcpf(1.f + __expf(-rf));
        float hc = xh + rf*rh;
        float e2 = __expf(2.f*hc);
        float th = 1.f - 2.f*__builtin_amdgcn_rcpf(e2 + 1.f);
        float hn = th + zf*(hpc[s][r] - th);
        hpc[s][r] = hn;
        u16 hbf = f2bf(hn);
        hb[cur^1][m][u] = hbf;
        if(MODE == 0)
          hop[r][s*16] = hbf;
        else if(step == T_LEN-1)
          h2out[(size_t)(b0+m)*(2*U_DIM) + dir*U_DIM + u] = hn;
      }
    }

    xqp += qstride;
    if(MODE==0){
      #pragma unroll
      for(int r=0;r<4;r++) hop[r] += hstride;
    }
    LBAR;
    cur ^= 1;
  }
}

// ---------------- final projection + softmax (f32 output) ---------------------
__global__ void out_softmax(const float* __restrict__ h2, const float* __restrict__ wout,
                            const float* __restrict__ bout, float* __restrict__ out)
{
  __shared__ float lg[C_DIM];
  int b = blockIdx.x, l = threadIdx.x;   // 64 threads = 1 wave
  float acc[C_DIM];
  #pragma unroll
  for(int c=0;c<C_DIM;c++) acc[c] = 0.f;
  for(int k=l; k<2*U_DIM; k+=64){
    float hv = h2[b*2*U_DIM + k];
    #pragma unroll
    for(int c=0;c<C_DIM;c++) acc[c] += hv * wout[k*C_DIM + c];
  }
  #pragma unroll
  for(int c=0;c<C_DIM;c++){
    float v = acc[c];
    for(int off=32; off; off>>=1) v += __shfl_down(v, off);
    if(l==0) lg[c] = v + bout[c];
  }
  __syncthreads();
  if(l==0){
    float mx = lg[0];
    for(int c=1;c<C_DIM;c++) mx = fmaxf(mx, lg[c]);
    float sum = 0.f, ex[C_DIM];
    for(int c=0;c<C_DIM;c++){ ex[c] = __expf(lg[c]-mx); sum += ex[c]; }
    for(int c=0;c<C_DIM;c++) out[b*C_DIM + c] = ex[c]/sum;
  }
}

extern "C" void kernel_launch(void* const* d_in, const int* in_sizes, int n_in,
                              void* d_out, int out_size, void* d_ws, size_t ws_size,
                              hipStream_t stream)
{
  const int*   x    = (const int*)d_in[0];
  const float* emb  = (const float*)d_in[1];
  const float* k1f  = (const float*)d_in[2];
  const float* rk1f = (const float*)d_in[3];
  const float* b1f  = (const float*)d_in[4];
  const float* k1b  = (const float*)d_in[5];
  const float* rk1b = (const float*)d_in[6];
  const float* b1b  = (const float*)d_in[7];
  const float* k2f  = (const float*)d_in[8];
  const float* rk2f = (const float*)d_in[9];
  const float* b2f  = (const float*)d_in[10];
  const float* k2b  = (const float*)d_in[11];
  const float* rk2b = (const float*)d_in[12];
  const float* b2b  = (const float*)d_in[13];
  const float* wout = (const float*)d_in[14];
  const float* bout = (const float*)d_in[15];

  char* ws = (char*)d_ws;
  u16*  k1t   = (u16*)(ws);                       // 983,040 B     [1536,320]
  u16*  k2t   = (u16*)(ws + 983040);              // 1,572,864 B   [1536,512]
  u16*  rkt   = (u16*)(ws + 2555904);             // 1,572,864 B   4x[768,256]
  float* h2   = (float*)(ws + 4128768);           // 131,072 B     [64,512]
  u16*  h1    = (u16*)(ws + 4259840);             // 33,554,432 B  [BT,512]
  u16*  e_pad = (u16*)(ws + 4259840);             // (alias h1)
  u16*  xq    = (u16*)(ws + 37814272);            // 100,663,296 B packed preacts

  transpose_cc<<<(NTOT*EP +255)/256,256,0,stream>>>(k1f, k1b, k1t, E_DIM, EP, NTOT);
  transpose_cc<<<(NTOT*512+255)/256,256,0,stream>>>(k2f, k2b, k2t, 512, 512, NTOT);
  transpose_cc<<<(G3*U_DIM+255)/256,256,0,stream>>>(rk1f, rk1f, rkt,                U_DIM, U_DIM, G3);
  transpose_cc<<<(G3*U_DIM+255)/256,256,0,stream>>>(rk1b, rk1b, rkt + 1*G3*U_DIM,   U_DIM, U_DIM, G3);
  transpose_cc<<<(G3*U_DIM+255)/256,256,0,stream>>>(rk2f, rk2f, rkt + 2*G3*U_DIM,   U_DIM, U_DIM, G3);
  transpose_cc<<<(G3*U_DIM+255)/256,256,0,stream>>>(rk2b, rk2b, rkt + 3*G3*U_DIM,   U_DIM, U_DIM, G3);

  embed_pad<<<(BT*EP)/256,256,0,stream>>>(x, emb, e_pad);

  // layer 1: xq = pack(e @ K1 + b0) ; scan -> h1
  gemm_bt<<<dim3(12,256),256,0,stream>>>(e_pad, k1t, xq, EP, b1f, b1b);
  gru_scan3<0><<<8,512,0,stream>>>(xq, rkt, b1f, b1b, h1, nullptr);

  // layer 2: xq = pack(h1 @ K2 + b0) ; scan -> h2 (final states only)
  gemm_bt<<<dim3(12,256),256,0,stream>>>(h1, k2t, xq, 512, b2f, b2b);
  gru_scan3<1><<<8,512,0,stream>>>(xq, rkt + 2*G3*U_DIM, b2f, b2b, nullptr, h2);

  out_softmax<<<64,64,0,stream>>>(h2, wout, bout, (float*)d_out);
}